// Round 13
// baseline (1280.457 us; speedup 1.0000x reference)
//
#include <hip/hip_runtime.h>
#include <cstdint>

typedef __attribute__((ext_vector_type(8))) _Float16 half8;  // 8 x fp16 (4 VGPRs)
typedef __attribute__((ext_vector_type(4))) _Float16 half4;  // 4 x fp16 (8B)
typedef __attribute__((ext_vector_type(4))) float f32x4;     // MFMA 16x16 accumulator
typedef unsigned short u16;
typedef unsigned int u32;
typedef unsigned long long u64;

#define MFMA16F(a, b, c) __builtin_amdgcn_mfma_f32_16x16x32_f16((a), (b), (c), 0, 0, 0)
#define AGENT __HIP_MEMORY_SCOPE_AGENT

// async global->LDS, 16B/lane. AUX: 0 = normal cached; 1 = SC0 (try: bypass
// L1, read own XCD L2); 17 = SC0|SC1 (bypass L1+L2, read LLC — r2-r11 proven
// to see agent-scope write-through stores from any XCD).
template <int AUX>
__device__ __forceinline__ void gl_lds16_a(const void* g, void* lds) {
  __builtin_amdgcn_global_load_lds(
      (const __attribute__((address_space(1))) unsigned*)g,
      (__attribute__((address_space(3))) unsigned*)lds, 16, 0, AUX);
}

__device__ __forceinline__ float sigm(float x) { return 1.f / (1.f + __expf(-x)); }
__device__ __forceinline__ float tanh_f(float x) { return 2.f / (1.f + __expf(-2.f * x)) - 1.f; }

// ---------------------------------------------------------------------------
__global__ void k_cvt(const float* __restrict__ in, _Float16* __restrict__ o, int n4) {
  int i = blockIdx.x * blockDim.x + threadIdx.x;
  int stride = gridDim.x * blockDim.x;
  for (; i < n4; i += stride) {
    float4 v = ((const float4*)in)[i];
    half4 h = {(_Float16)v.x, (_Float16)v.y, (_Float16)v.z, (_Float16)v.w};
    ((half4*)o)[i] = h;
  }
}

__global__ void k_bias(const float* __restrict__ bi, const float* __restrict__ bh,
                       float* __restrict__ bias) {
  int i = blockIdx.x * blockDim.x + threadIdx.x;
  if (i < 4096) bias[i] = bi[i] + bh[i];
}

// init h slots (256KB): slot 0 = zeros (valid h(0), parity 0); slots 1-3
// poisoned LSB=1. agent-scope; dispatch-boundary acquire invalidates caches
// so k_scan sees these on both read paths.
__global__ void k_init4(u64* __restrict__ hf) {
  const int i = blockIdx.x * blockDim.x + threadIdx.x;  // 32768 u64
  const u64 v = (i < 8192) ? 0ull : 0x0001000100010001ull;
  __hip_atomic_store(&hf[i], v, __ATOMIC_RELAXED, AGENT);
}

// ---------------------------------------------------------------------------
// GEMM1: xg = x.W_ih^T + bias  (M=16384, N=4096, K=1024), fp16 out in scan
// layout [l][s][j][gate]. m97 structure w/ 16B-slot XOR swizzle (r6-verified).
__global__ __launch_bounds__(256) void k_gemm1(
    const u16* __restrict__ Aw, const u16* __restrict__ Bw,
    const float* __restrict__ bias, _Float16* __restrict__ xg) {
  __shared__ u16 sA[4096];  // 8KB: 128 rows x 32 k (64B rows, swizzled 16B slots)
  __shared__ u16 sB[4096];
  const int tid = threadIdx.x, lane = tid & 63, wid = tid >> 6;
  const int bm = blockIdx.x >> 5, bn = blockIdx.x & 31;
  const int m0 = bm * 128, n0 = bn * 128;
  const int wr = wid >> 1, wc = wid & 1;
  f32x4 acc[4][4] = {};

  for (int kt = 0; kt < 32; ++kt) {
#pragma unroll
    for (int rb = 0; rb < 2; ++rb) {  // stage A+B: 2 rounds x 1KB per wave each
      const int base = (rb * 4 + wid) * 1024;
      const int b = base + lane * 16;
      const int row = b >> 6;                       // tile row
      const int q = lane & 3;                       // 16B slot in row
      const int sq = ((q - row) & 3) << 4;          // inverse-swizzled source slot
      gl_lds16_a<0>((const char*)Aw + (size_t)(m0 + row) * 2048 + (size_t)kt * 64 + sq,
                    (char*)&sA[0] + base);
      gl_lds16_a<0>((const char*)Bw + (size_t)(n0 + row) * 2048 + (size_t)kt * 64 + sq,
                    (char*)&sB[0] + base);
    }
    __syncthreads();
    half8 ah[4], bh[4];
#pragma unroll
    for (int i = 0; i < 4; ++i) {
      const int ra = wr * 64 + i * 16 + (lane & 15);
      ah[i] = *(const half8*)((const char*)sA + ra * 64 + ((((lane >> 4) + ra) & 3) << 4));
      const int rb2 = wc * 64 + i * 16 + (lane & 15);
      bh[i] = *(const half8*)((const char*)sB + rb2 * 64 + ((((lane >> 4) + rb2) & 3) << 4));
    }
#pragma unroll
    for (int i = 0; i < 4; ++i)
#pragma unroll
      for (int j = 0; j < 4; ++j) acc[i][j] = MFMA16F(ah[i], bh[j], acc[i][j]);
    __syncthreads();
  }

  // epilogue: C/D col=lane&15, row=(lane>>4)*4+q [m89]; scatter to [l][s][j][gate]
#pragma unroll
  for (int j = 0; j < 4; ++j) {
    const int gcol = n0 + wc * 64 + j * 16 + (lane & 15);
    const int gate = gcol >> 10, jj = gcol & 1023;
    const float bv = bias[gcol];
#pragma unroll
    for (int i = 0; i < 4; ++i)
#pragma unroll
      for (int q = 0; q < 4; ++q) {
        const int m = m0 + wr * 64 + i * 16 + (lane >> 4) * 4 + q;
        const int b = m >> 11, t = m & 2047;
        const int s = (b << 2) | (t & 3);
        const int l = t >> 2;
        xg[(((size_t)(l * 32 + s)) * 1024 + jj) * 4 + gate] = (_Float16)(acc[i][j][q] + bv);
      }
  }
}

// ---------------------------------------------------------------------------
// Persistent scan v9 (speculative data-as-flag + adaptive read path):
// 256 blocks (1/CU), group gr = b&7 (gr>=4 exits) -> co-XCD IF dispatch is
// round-robin; wl = b>>3 in [0,32). Protocol identical to r11 (proven):
// publish = agent-scope write-through u64, stage = speculative + parity
// check + retry, ONE __syncthreads per step. NEW: stage first tries aux=1
// (own-L2 read; fresh if write-through updated it); >64 failed attempts in
// a step => permanent per-WG fallback to aux=17 (exact r11 path). Liveness
// is unconditional; correctness guarded by the parity check (no silent
// 8-step alias: a 4-step-stale hit mismatches first and triggers fallback).
__global__ __launch_bounds__(512, 1) void k_scan(
    const u16* __restrict__ Whh16, const _Float16* __restrict__ xg,
    u16* __restrict__ hfrag, float* __restrict__ out) {
  const int b = blockIdx.x;
  const int gr = b & 7;
  if (gr >= 4) return;           // spare half of the CUs idles
  const int wl = b >> 3;         // 0..31
  const int tid = threadIdx.x;

  __shared__ u16 h_lds[2][8192];  // 2 x 16KB double buffer
  const int lane = tid & 63, wid = tid >> 6;  // 8 waves
  const int j0 = wl * 32;                     // 32 hidden cols

  // stationary W fragments: lane p=lane&15 -> gate=p>>2, local col c=p&3
  half8 wf[32];
  {
    const int p = lane & 15;
    const int gate = p >> 2, c = p & 3;
    const int koff = (lane >> 4) * 8;
    const size_t rowbase = (size_t)(gate * 1024 + j0 + wid * 4 + c) * 1024;
#pragma unroll
    for (int ks = 0; ks < 32; ++ks) {
      wf[ks] = *(const half8*)(Whh16 + rowbase + ks * 32 + koff);
      asm volatile("" : "+v"(wf[ks]));  // opaque: stays in register file
    }
  }

  // cell ownership (lanes 0-31; 32-63 hold duplicate MFMA rows)
  const int m = ((lane >> 4) << 2) | ((lane >> 2) & 3);  // chain (local, 0..7)
  const int jl = (wid << 2) | (lane & 3);                // local hidden col
  const int s = gr * 8 + m;                              // global chain
  const int j = j0 + jl;                                 // global hidden col
  float c_reg = 0.f;
  const int hq = wl * 64 + (wid >> 1) * 16 + m * 2 + (wid & 1);

  const u64 M = 0x0001000100010001ull;
  int mode = 0;  // 0: aux=1 own-L2 read; 1: aux=17 LLC read (r11-proven)

  // xg pipeline: preload step 0
  float x0 = 0.f, x1 = 0.f, x2 = 0.f, x3 = 0.f;
  if (lane < 32) {
    const half4 xv = *(const half4*)(xg + ((size_t)s * 1024 + j) * 4);
    x0 = (float)xv[0]; x1 = (float)xv[1]; x2 = (float)xv[2]; x3 = (float)xv[3];
  }

  for (int l = 0; l < 512; ++l) {
    const char* hsrc = (const char*)hfrag + (size_t)(l & 3) * 65536 + gr * 16384;
    u64* hdst = (u64*)((char*)hfrag + (size_t)((l + 1) & 3) * 65536 + gr * 16384);
    const u64 expv = ((l >> 2) & 1) ? M : 0ull;     // expected read parity
    const u32 pw = (u32)(((l + 1) >> 2) & 1);       // publish parity
    u16* ldsb = &h_lds[l & 1][0];

    // --- speculative stage own 2KB + parity check; bounded-adaptive retry ---
    {
      int tries = 0;
      for (;;) {
        if (mode == 0) {
#pragma unroll
          for (int r = 0; r < 2; ++r)
            gl_lds16_a<1>(hsrc + wid * 2048 + r * 1024 + lane * 16,
                          (char*)ldsb + wid * 2048 + r * 1024);
        } else {
#pragma unroll
          for (int r = 0; r < 2; ++r)
            gl_lds16_a<17>(hsrc + wid * 2048 + r * 1024 + lane * 16,
                           (char*)ldsb + wid * 2048 + r * 1024);
        }
        asm volatile("s_waitcnt vmcnt(0)" ::: "memory");
        bool ok = true;
#pragma unroll
        for (int r = 0; r < 2; ++r) {
          const u64* q = (const u64*)((const char*)ldsb + wid * 2048 + r * 1024 + lane * 16);
          ok = ok & (((q[0] ^ expv) & M) == 0) & (((q[1] ^ expv) & M) == 0);
        }
        if (__all(ok)) break;
        if (++tries > 64) mode = 1;  // permanent LLC fallback: liveness
      }
    }
    __syncthreads();  // the only per-step barrier

    // --- gates = h . W^T : 4 independent accumulator chains, W pinned ---
    f32x4 a0 = {0.f, 0.f, 0.f, 0.f}, a1 = a0, a2 = a0, a3 = a0;
    const char* ab = (const char*)ldsb + (lane >> 4) * 128 + (lane & 7) * 16;
#pragma unroll
    for (int ks = 0; ks < 32; ks += 4) {
      const char* cb = ab + ks * 512;
      a0 = MFMA16F(*(const half8*)(cb), wf[ks], a0);
      a1 = MFMA16F(*(const half8*)(cb + 512), wf[ks + 1], a1);
      a2 = MFMA16F(*(const half8*)(cb + 1024), wf[ks + 2], a2);
      a3 = MFMA16F(*(const half8*)(cb + 1536), wf[ks + 3], a3);
    }
    float G0 = (a0[0] + a1[0]) + (a2[0] + a3[0]);
    float G1 = (a0[1] + a1[1]) + (a2[1] + a3[1]);
    float G2 = (a0[2] + a1[2]) + (a2[2] + a3[2]);
    float G3 = (a0[3] + a1[3]) + (a2[3] + a3[3]);

    // --- 4x4 lane/register transpose (lane bits 2-3 <-> reg bits) ---
    {
      const bool h2 = (lane & 4) != 0;
      float x, y;
      x = h2 ? G0 : G1; y = __shfl_xor(x, 4);
      G0 = h2 ? y : G0; G1 = h2 ? G1 : y;
      x = h2 ? G2 : G3; y = __shfl_xor(x, 4);
      G2 = h2 ? y : G2; G3 = h2 ? G3 : y;
    }
    {
      const bool h3 = (lane & 8) != 0;
      float x, y;
      x = h3 ? G0 : G2; y = __shfl_xor(x, 8);
      G0 = h3 ? y : G0; G2 = h3 ? G2 : y;
      x = h3 ? G1 : G3; y = __shfl_xor(x, 8);
      G1 = h3 ? y : G1; G3 = h3 ? G3 : y;
    }

    // --- LSTM cell (i,f,g,o) ---
    const float gi = G0 + x0, gf = G1 + x1, gg = G2 + x2, go = G3 + x3;
    const float iv = sigm(gi), fv = sigm(gf), gv = tanh_f(gg), ov = sigm(go);
    c_reg = fv * c_reg + iv * gv;
    const float hv = ov * tanh_f(c_reg);

    if (lane < 32) {
      // --- publish FIRST: parity-forced u64 pack, agent write-through ---
      u32 hb = (u32)__builtin_bit_cast(u16, (_Float16)hv);
      hb = (hb & 0xFFFEu) | pw;
      const u32 o1 = (u32)__shfl_xor((int)hb, 1);
      const u32 w1 = (lane & 1) ? ((o1 & 0xFFFFu) | (hb << 16))
                                : ((hb & 0xFFFFu) | (o1 << 16));
      const u32 o2lo = (u32)__shfl_xor((int)w1, 2);
      const u64 v = (lane & 2) ? (((u64)w1 << 32) | (u64)o2lo)
                               : (((u64)o2lo << 32) | (u64)w1);
      if ((lane & 3) == 0)
        __hip_atomic_store(&hdst[hq], v, __ATOMIC_RELAXED, AGENT);

      // out store (plain cached; ack absorbed by next stage's vmcnt)
      out[(((size_t)(s >> 2) * 2048) + (size_t)l * 4 + (s & 3)) * 1024 + j] = hv;

      // next-step xg prefetch
      if (l < 511) {
        const half4 xv = *(const half4*)(xg + (((size_t)(l + 1) * 32 + s) * 1024 + j) * 4);
        x0 = (float)xv[0]; x1 = (float)xv[1]; x2 = (float)xv[2]; x3 = (float)xv[3];
      }
    }
  }
}

// ---------------------------------------------------------------------------
extern "C" void kernel_launch(void* const* d_in, const int* in_sizes, int n_in,
                              void* d_out, int out_size, void* d_ws, size_t ws_size,
                              hipStream_t stream) {
  const float* x   = (const float*)d_in[0];
  const float* Wih = (const float*)d_in[1];
  const float* Whh = (const float*)d_in[2];
  const float* bih = (const float*)d_in[3];
  const float* bhh = (const float*)d_in[4];
  float* out = (float*)d_out;
  char* ws = (char*)d_ws;

  constexpr size_t OFF_WIH16 = 0;                 //  8388608
  constexpr size_t OFF_WHH16 = 8388608;           //  8388608
  constexpr size_t OFF_BIAS  = 16777216;          //    16384
  constexpr size_t OFF_HFRAG = 16793600;          //   262144 (4 slots x 4 groups x 16KB)
  constexpr size_t OFF_XG    = 17055744;          // 134217728 (fp16)
  constexpr size_t WS_NEED   = OFF_XG + 134217728;  // 151,273,472

  if (ws_size < WS_NEED) {  // canary: absmax reads exactly 0.9140625
    hipMemsetAsync(d_out, 0, (size_t)out_size * sizeof(float), stream);
    return;
  }

  _Float16* wih16 = (_Float16*)(ws + OFF_WIH16);
  _Float16* whh16 = (_Float16*)(ws + OFF_WHH16);
  float* bias = (float*)(ws + OFF_BIAS);
  u16* hfrag = (u16*)(ws + OFF_HFRAG);
  _Float16* xg = (_Float16*)(ws + OFF_XG);
  // x16 scratch lives in d_out (67MB >= 33.5MB); scan fully overwrites out later
  _Float16* x16 = (_Float16*)d_out;

  k_cvt<<<1024, 256, 0, stream>>>(Wih, wih16, 4194304 / 4);
  k_cvt<<<1024, 256, 0, stream>>>(Whh, whh16, 4194304 / 4);
  k_cvt<<<2048, 256, 0, stream>>>(x, x16, 16777216 / 4);
  k_bias<<<16, 256, 0, stream>>>(bih, bhh, bias);
  k_init4<<<128, 256, 0, stream>>>((u64*)hfrag);
  k_gemm1<<<4096, 256, 0, stream>>>((const u16*)x16, (const u16*)wih16, bias, xg);
  k_scan<<<256, 512, 0, stream>>>((const u16*)whh16, xg, hfrag, out);
}

// Round 14
// 1272.189 us; speedup vs baseline: 1.0065x; 1.0065x over previous
//
#include <hip/hip_runtime.h>
#include <cstdint>

typedef __attribute__((ext_vector_type(8))) _Float16 half8;  // 8 x fp16 (4 VGPRs)
typedef __attribute__((ext_vector_type(4))) _Float16 half4;  // 4 x fp16 (8B)
typedef __attribute__((ext_vector_type(4))) float f32x4;     // MFMA 16x16 accumulator
typedef unsigned short u16;
typedef unsigned int u32;
typedef unsigned long long u64;

#define MFMA16F(a, b, c) __builtin_amdgcn_mfma_f32_16x16x32_f16((a), (b), (c), 0, 0, 0)
#define AGENT __HIP_MEMORY_SCOPE_AGENT

// async global->LDS, 16B/lane. AUX: 0 = cached; 1 = SC0 (bypass L1, read own
// XCD L2 — r13-proven to see agent write-through stores from same XCD);
// 17 = SC0|SC1 (bypass L1+L2, read LLC — r11-proven for any XCD).
template <int AUX>
__device__ __forceinline__ void gl_lds16_a(const void* g, void* lds) {
  __builtin_amdgcn_global_load_lds(
      (const __attribute__((address_space(1))) unsigned*)g,
      (__attribute__((address_space(3))) unsigned*)lds, 16, 0, AUX);
}

__device__ __forceinline__ float sigm(float x) { return 1.f / (1.f + __expf(-x)); }
__device__ __forceinline__ float tanh_f(float x) { return 2.f / (1.f + __expf(-2.f * x)) - 1.f; }

// ---------------------------------------------------------------------------
__global__ void k_cvt(const float* __restrict__ in, _Float16* __restrict__ o, int n4) {
  int i = blockIdx.x * blockDim.x + threadIdx.x;
  int stride = gridDim.x * blockDim.x;
  for (; i < n4; i += stride) {
    float4 v = ((const float4*)in)[i];
    half4 h = {(_Float16)v.x, (_Float16)v.y, (_Float16)v.z, (_Float16)v.w};
    ((half4*)o)[i] = h;
  }
}

__global__ void k_bias(const float* __restrict__ bi, const float* __restrict__ bh,
                       float* __restrict__ bias) {
  int i = blockIdx.x * blockDim.x + threadIdx.x;
  if (i < 4096) bias[i] = bi[i] + bh[i];
}

// init h slots (256KB = 4 slots x 8 groups x 8KB): slot 0 = zeros (valid h(0),
// parity 0); slots 1-3 poisoned LSB=1. Also zero the 16 rendezvous words.
__global__ void k_init4(u64* __restrict__ hf, u32* __restrict__ rdz) {
  const int i = blockIdx.x * blockDim.x + threadIdx.x;  // 32768 u64
  const u64 v = (i < 8192) ? 0ull : 0x0001000100010001ull;
  __hip_atomic_store(&hf[i], v, __ATOMIC_RELAXED, AGENT);
  if (i < 16) __hip_atomic_store(&rdz[i], 0u, __ATOMIC_RELAXED, AGENT);
}

// ---------------------------------------------------------------------------
// GEMM1: xg = x.W_ih^T + bias  (M=16384, N=4096, K=1024), fp16 out in scan
// layout [l][s][j][gate]. m97 structure w/ 16B-slot XOR swizzle (r6-verified).
__global__ __launch_bounds__(256) void k_gemm1(
    const u16* __restrict__ Aw, const u16* __restrict__ Bw,
    const float* __restrict__ bias, _Float16* __restrict__ xg) {
  __shared__ u16 sA[4096];  // 8KB: 128 rows x 32 k (64B rows, swizzled 16B slots)
  __shared__ u16 sB[4096];
  const int tid = threadIdx.x, lane = tid & 63, wid = tid >> 6;
  const int bm = blockIdx.x >> 5, bn = blockIdx.x & 31;
  const int m0 = bm * 128, n0 = bn * 128;
  const int wr = wid >> 1, wc = wid & 1;
  f32x4 acc[4][4] = {};

  for (int kt = 0; kt < 32; ++kt) {
#pragma unroll
    for (int rb = 0; rb < 2; ++rb) {  // stage A+B: 2 rounds x 1KB per wave each
      const int base = (rb * 4 + wid) * 1024;
      const int b = base + lane * 16;
      const int row = b >> 6;                       // tile row
      const int q = lane & 3;                       // 16B slot in row
      const int sq = ((q - row) & 3) << 4;          // inverse-swizzled source slot
      gl_lds16_a<0>((const char*)Aw + (size_t)(m0 + row) * 2048 + (size_t)kt * 64 + sq,
                    (char*)&sA[0] + base);
      gl_lds16_a<0>((const char*)Bw + (size_t)(n0 + row) * 2048 + (size_t)kt * 64 + sq,
                    (char*)&sB[0] + base);
    }
    __syncthreads();
    half8 ah[4], bh[4];
#pragma unroll
    for (int i = 0; i < 4; ++i) {
      const int ra = wr * 64 + i * 16 + (lane & 15);
      ah[i] = *(const half8*)((const char*)sA + ra * 64 + ((((lane >> 4) + ra) & 3) << 4));
      const int rb2 = wc * 64 + i * 16 + (lane & 15);
      bh[i] = *(const half8*)((const char*)sB + rb2 * 64 + ((((lane >> 4) + rb2) & 3) << 4));
    }
#pragma unroll
    for (int i = 0; i < 4; ++i)
#pragma unroll
      for (int j = 0; j < 4; ++j) acc[i][j] = MFMA16F(ah[i], bh[j], acc[i][j]);
    __syncthreads();
  }

  // epilogue: C/D col=lane&15, row=(lane>>4)*4+q [m89]; scatter to [l][s][j][gate]
#pragma unroll
  for (int j = 0; j < 4; ++j) {
    const int gcol = n0 + wc * 64 + j * 16 + (lane & 15);
    const int gate = gcol >> 10, jj = gcol & 1023;
    const float bv = bias[gcol];
#pragma unroll
    for (int i = 0; i < 4; ++i)
#pragma unroll
      for (int q = 0; q < 4; ++q) {
        const int m = m0 + wr * 64 + i * 16 + (lane >> 4) * 4 + q;
        const int b = m >> 11, t = m & 2047;
        const int s = (b << 2) | (t & 3);
        const int l = t >> 2;
        xg[(((size_t)(l * 32 + s)) * 1024 + jj) * 4 + gate] = (_Float16)(acc[i][j][q] + bv);
      }
  }
}

// ---------------------------------------------------------------------------
// Persistent scan v10: 8 groups x 32 WGs x 512 thr, M=4 chains/group.
// Grouping by RUNTIME RENDEZVOUS: block posts HW_REG_XCC_ID, takes a rank on
// its XCD; if every XCD got exactly 32 blocks, group = physical XCD (all
// exchange co-L2) else fixed fallback mapping in LLC mode. Protocol = r11's
// proven speculative data-as-flag (parity LSB, 4 slots, 1 barrier/step) with
// r13's per-WG adaptive read path (aux=1, >64 fails -> aux=17 permanently).
// Group h slice = 8KB: layout [ks=j>>5][m(4)][k(32 fp16)]; WG wl's publish
// (cols [32wl,32wl+32), 4 chains) = slice ks=wl = contiguous 256B.
__global__ __launch_bounds__(512, 1) void k_scan(
    const u16* __restrict__ Whh16, const _Float16* __restrict__ xg,
    u16* __restrict__ hfrag, float* __restrict__ out, u32* __restrict__ rdz) {
  const int b = blockIdx.x;
  const int tid = threadIdx.x;
  const int lane = tid & 63, wid = tid >> 6;  // 8 waves

  __shared__ u16 h_lds[2][4096];  // 2 x 8KB double buffer
  __shared__ u32 sh_gr, sh_wl, sh_mode;

  // --- rendezvous: always terminates (monotonic counter to 256) ---
  if (tid == 0) {
    u32 my;
    asm volatile("s_getreg_b32 %0, hwreg(HW_REG_XCC_ID)" : "=s"(my));
    my &= 7u;
    const u32 rank = __hip_atomic_fetch_add(&rdz[my], 1u, __ATOMIC_RELAXED, AGENT);
    __hip_atomic_fetch_add(&rdz[8], 1u, __ATOMIC_RELAXED, AGENT);
    while (__hip_atomic_load(&rdz[8], __ATOMIC_RELAXED, AGENT) < 256u)
      __builtin_amdgcn_s_sleep(1);
    u32 okloc = 1;
    for (int x = 0; x < 8; ++x)
      okloc &= (__hip_atomic_load(&rdz[x], __ATOMIC_RELAXED, AGENT) == 32u);
    sh_gr = okloc ? my : (u32)(b >> 5);
    sh_wl = okloc ? rank : (u32)(b & 31);
    sh_mode = okloc ? 0u : 1u;  // 0: own-L2 reads; 1: LLC reads
  }
  __syncthreads();
  const int gr = (int)sh_gr, wl = (int)sh_wl;
  int mode = (int)sh_mode;
  const int j0 = wl * 32;

  // stationary W fragments: lane p=lane&15 -> gate=p>>2, col c=p&3;
  // wave's 4 cols are j0 + 4*wid + c. 128 VGPRs, pinned opaque.
  half8 wf[32];
  {
    const int p = lane & 15;
    const int gate = p >> 2, c = p & 3;
    const int koff = (lane >> 4) * 8;
    const size_t rowbase = (size_t)(gate * 1024 + j0 + wid * 4 + c) * 1024;
#pragma unroll
    for (int ks = 0; ks < 32; ++ks) {
      wf[ks] = *(const half8*)(Whh16 + rowbase + ks * 32 + koff);
      asm volatile("" : "+v"(wf[ks]));
    }
  }

  // cell ownership: lanes 0-15 (C rows 0-3 = the 4 real chains; rows 4-15 dup)
  const int m = (lane >> 2) & 3;           // chain (local, 0..3)
  const int jl = (wid << 2) | (lane & 3);  // local hidden col (0..31)
  const int s = gr * 4 + m;                // global chain
  const int j = j0 + jl;                   // global hidden col
  float c_reg = 0.f;
  const int hq = wl * 32 + m * 8 + wid;    // publish u64 idx in group slice

  const u64 M = 0x0001000100010001ull;

  // xg pipeline: preload step 0
  float x0 = 0.f, x1 = 0.f, x2 = 0.f, x3 = 0.f;
  if (lane < 16) {
    const half4 xv = *(const half4*)(xg + ((size_t)s * 1024 + j) * 4);
    x0 = (float)xv[0]; x1 = (float)xv[1]; x2 = (float)xv[2]; x3 = (float)xv[3];
  }

  for (int l = 0; l < 512; ++l) {
    const char* hsrc = (const char*)hfrag + (size_t)(l & 3) * 65536 + gr * 8192;
    u64* hdst = (u64*)((char*)hfrag + (size_t)((l + 1) & 3) * 65536 + gr * 8192);
    const u64 expv = ((l >> 2) & 1) ? M : 0ull;     // expected read parity
    const u32 pw = (u32)(((l + 1) >> 2) & 1);       // publish parity
    u16* ldsb = &h_lds[l & 1][0];

    // --- speculative stage: ONE gl_lds16 per lane (1KB/wave, 8KB total) ---
    {
      int tries = 0;
      for (;;) {
        if (mode == 0)
          gl_lds16_a<1>(hsrc + wid * 1024 + lane * 16, (char*)ldsb + wid * 1024);
        else
          gl_lds16_a<17>(hsrc + wid * 1024 + lane * 16, (char*)ldsb + wid * 1024);
        asm volatile("s_waitcnt vmcnt(0)" ::: "memory");
        const u64* q = (const u64*)((const char*)ldsb + wid * 1024 + lane * 16);
        const bool ok = (((q[0] ^ expv) & M) == 0) & (((q[1] ^ expv) & M) == 0);
        if (__all(ok)) break;
        if (++tries > 64) mode = 1;  // permanent LLC fallback: liveness
      }
    }
    __syncthreads();  // the only per-step barrier

    // --- gates = h . W^T : 4 accumulator chains; A rows 4-15 duplicate ---
    // A-frag addr: ks*256 + (row&3)*64 + (lane>>4)*16
    f32x4 a0 = {0.f, 0.f, 0.f, 0.f}, a1 = a0, a2 = a0, a3 = a0;
    const char* ab = (const char*)ldsb + (lane & 3) * 64 + (lane >> 4) * 16;
#pragma unroll
    for (int ks = 0; ks < 32; ks += 4) {
      const char* cb = ab + ks * 256;
      a0 = MFMA16F(*(const half8*)(cb), wf[ks], a0);
      a1 = MFMA16F(*(const half8*)(cb + 256), wf[ks + 1], a1);
      a2 = MFMA16F(*(const half8*)(cb + 512), wf[ks + 2], a2);
      a3 = MFMA16F(*(const half8*)(cb + 768), wf[ks + 3], a3);
    }
    float G0 = (a0[0] + a1[0]) + (a2[0] + a3[0]);
    float G1 = (a0[1] + a1[1]) + (a2[1] + a3[1]);
    float G2 = (a0[2] + a1[2]) + (a2[2] + a3[2]);
    float G3 = (a0[3] + a1[3]) + (a2[3] + a3[3]);

    // --- 4x4 lane/register transpose (lane bits 2-3 <-> reg bits) ---
    {
      const bool h2 = (lane & 4) != 0;
      float x, y;
      x = h2 ? G0 : G1; y = __shfl_xor(x, 4);
      G0 = h2 ? y : G0; G1 = h2 ? G1 : y;
      x = h2 ? G2 : G3; y = __shfl_xor(x, 4);
      G2 = h2 ? y : G2; G3 = h2 ? G3 : y;
    }
    {
      const bool h3 = (lane & 8) != 0;
      float x, y;
      x = h3 ? G0 : G2; y = __shfl_xor(x, 8);
      G0 = h3 ? y : G0; G2 = h3 ? G2 : y;
      x = h3 ? G1 : G3; y = __shfl_xor(x, 8);
      G1 = h3 ? y : G1; G3 = h3 ? G3 : y;
    }

    // --- LSTM cell (i,f,g,o) ---
    const float gi = G0 + x0, gf = G1 + x1, gg = G2 + x2, go = G3 + x3;
    const float iv = sigm(gi), fv = sigm(gf), gv = tanh_f(gg), ov = sigm(go);
    c_reg = fv * c_reg + iv * gv;
    const float hv = ov * tanh_f(c_reg);

    if (lane < 16) {
      // --- publish FIRST: parity-forced u64 pack (c bits 0-1), agent WT ---
      u32 hb = (u32)__builtin_bit_cast(u16, (_Float16)hv);
      hb = (hb & 0xFFFEu) | pw;
      const u32 o1 = (u32)__shfl_xor((int)hb, 1);
      const u32 w1 = (lane & 1) ? ((o1 & 0xFFFFu) | (hb << 16))
                                : ((hb & 0xFFFFu) | (o1 << 16));
      const u32 o2lo = (u32)__shfl_xor((int)w1, 2);
      const u64 v = (lane & 2) ? (((u64)w1 << 32) | (u64)o2lo)
                               : (((u64)o2lo << 32) | (u64)w1);
      if ((lane & 3) == 0)
        __hip_atomic_store(&hdst[hq], v, __ATOMIC_RELAXED, AGENT);

      // out store (plain cached; ack absorbed by next stage's vmcnt)
      out[(((size_t)(s >> 2) * 2048) + (size_t)l * 4 + (s & 3)) * 1024 + j] = hv;

      // next-step xg prefetch
      if (l < 511) {
        const half4 xv = *(const half4*)(xg + (((size_t)(l + 1) * 32 + s) * 1024 + j) * 4);
        x0 = (float)xv[0]; x1 = (float)xv[1]; x2 = (float)xv[2]; x3 = (float)xv[3];
      }
    }
  }
}

// ---------------------------------------------------------------------------
extern "C" void kernel_launch(void* const* d_in, const int* in_sizes, int n_in,
                              void* d_out, int out_size, void* d_ws, size_t ws_size,
                              hipStream_t stream) {
  const float* x   = (const float*)d_in[0];
  const float* Wih = (const float*)d_in[1];
  const float* Whh = (const float*)d_in[2];
  const float* bih = (const float*)d_in[3];
  const float* bhh = (const float*)d_in[4];
  float* out = (float*)d_out;
  char* ws = (char*)d_ws;

  constexpr size_t OFF_WIH16 = 0;                 //  8388608
  constexpr size_t OFF_WHH16 = 8388608;           //  8388608
  constexpr size_t OFF_BIAS  = 16777216;          //    16384
  constexpr size_t OFF_HFRAG = 16793600;          //   262144 (4 slots x 8 groups x 8KB)
  constexpr size_t OFF_RDZ   = 17055744;          //       64
  constexpr size_t OFF_XG    = 17055808;          // 134217728 (fp16)
  constexpr size_t WS_NEED   = OFF_XG + 134217728;  // 151,273,536

  if (ws_size < WS_NEED) {  // canary: absmax reads exactly 0.9140625
    hipMemsetAsync(d_out, 0, (size_t)out_size * sizeof(float), stream);
    return;
  }

  _Float16* wih16 = (_Float16*)(ws + OFF_WIH16);
  _Float16* whh16 = (_Float16*)(ws + OFF_WHH16);
  float* bias = (float*)(ws + OFF_BIAS);
  u16* hfrag = (u16*)(ws + OFF_HFRAG);
  u32* rdz = (u32*)(ws + OFF_RDZ);
  _Float16* xg = (_Float16*)(ws + OFF_XG);
  // x16 scratch lives in d_out (67MB >= 33.5MB); scan fully overwrites out later
  _Float16* x16 = (_Float16*)d_out;

  k_cvt<<<1024, 256, 0, stream>>>(Wih, wih16, 4194304 / 4);
  k_cvt<<<1024, 256, 0, stream>>>(Whh, whh16, 4194304 / 4);
  k_cvt<<<2048, 256, 0, stream>>>(x, x16, 16777216 / 4);
  k_bias<<<16, 256, 0, stream>>>(bih, bhh, bias);
  k_init4<<<128, 256, 0, stream>>>((u64*)hfrag, rdz);
  k_gemm1<<<4096, 256, 0, stream>>>((const u16*)x16, (const u16*)wih16, bias, xg);
  k_scan<<<256, 512, 0, stream>>>((const u16*)whh16, xg, hfrag, out, rdz);
}